// Round 13
// baseline (140.637 us; speedup 1.0000x reference)
//
#include <hip/hip_runtime.h>

typedef unsigned int u32;
typedef unsigned short u16;
typedef unsigned char u8;
typedef unsigned long long u64;

typedef __attribute__((ext_vector_type(8))) short bf16x8;
typedef __attribute__((ext_vector_type(4))) float f32x4;

#define L_SEQ 200

// Measured: f32 inputs (R6); MFMA 16x16x32_bf16 layouts verified (R6..R12,
// absmax 3.05e-5); low VGPR caps spill (R7); bf16-emb ws table -14us (R11);
// wave=attr -35us (R12). R12 residue: 3-wave blocks + terminal barrier hold
// slots at sample granularity -> R13: one-wave blocks (no barriers), rep
// round-trip through ws, separate epilogue kernel.
__device__ __forceinline__ u16 f2bf(float f) {
    u32 u = __float_as_uint(f);
    return (u16)((u + 0x7FFFu + ((u >> 16) & 1u)) >> 16);  // RNE
}
__device__ __forceinline__ u32 pk2bf(float fx, float fy) {  // round-half-up pair pack
    u32 xb = __float_as_uint(fx) + 0x8000u;
    u32 yb = __float_as_uint(fy) + 0x8000u;
    return __byte_perm(xb, yb, 0x7632);
}
__device__ __forceinline__ float wave_sumf(float v) {
#pragma unroll
    for (int off = 32; off; off >>= 1) v += __shfl_xor(v, off, 64);
    return v;
}

// ws layout (bytes): [0,24576) bf16 B-frag image; [24576,40960) len[Bn];
// [40960, 40960+Vn*128) bf16 emb table; [40960+Vn*128, +Bn*768) rep f32.
__global__ __launch_bounds__(256) void etna_prep(const void* __restrict__ xmask,
                                                 const float* __restrict__ tranW,
                                                 const float* __restrict__ emb,
                                                 void* __restrict__ ws, int Bn, int Vn) {
    const int tid = threadIdx.x;
    const int bid = blockIdx.x;

    // emb f32 -> bf16 (grid-stride, coalesced u64 stores)
    {
        u64* dst = (u64*)((char*)ws + 40960);
        const float4* src = (const float4*)emb;
        int ng = Vn * 16;
        for (int i = bid * 256 + tid; i < ng; i += gridDim.x * 256) {
            float4 v = src[i];
            u64 lo = pk2bf(v.x, v.y);
            u64 hi = pk2bf(v.z, v.w);
            dst[i] = lo | (hi << 32);
        }
    }

    if (bid < 48) {
        // B-frag image: element j of frag (a,c,kh,lane) =
        // tranW[a][kh*32+(lane>>4)*8+j][c*16+(lane&15)]  (contiguous writes)
        int it = bid * 256 + tid;
        int jj = it & 7;
        int ln = (it >> 3) & 63;
        int kh = (it >> 9) & 1;
        int c = (it >> 10) & 3;
        int a = it >> 12;
        int k = kh * 32 + (ln >> 4) * 8 + jj;
        int n = c * 16 + (ln & 15);
        ((u16*)ws)[it] = f2bf(tranW[a * 4096 + k * 64 + n]);
        return;
    }

    // x_mask encoding detection (first 800 bytes; safe for u8/bf16/f32/i32)
    const int wv = tid >> 6;
    const int lane = tid & 63;
    int esz;
    {
        u32 accF = 0, acc0 = 0, accO = 0;
#pragma unroll
        for (int k = 0; k < 4; ++k) {
            int i = lane + 64 * k;
            u32 w = (i < 200) ? ((const u32*)xmask)[i] : 0u;
            accF |= (w & 0xFEFEFEFEu);
            acc0 |= (w & 0x000000FFu);
            accO |= (w & 0xFFFFFF00u);
        }
        bool isFloat = __ballot(accF != 0) != 0;
        bool hasB0   = __ballot(acc0 != 0) != 0;
        bool hasOdd  = __ballot(accO != 0) != 0;
        esz = isFloat ? (hasB0 ? 2 : 4) : (hasOdd ? 1 : 4);
    }
    int s = (bid - 48) * 4 + wv;  // one wave per sample
    if (s < Bn) {
        int len = 0;
        int mbase = s * L_SEQ;
#pragma unroll
        for (int c4 = 0; c4 < 4; ++c4) {
            int l = c4 * 64 + lane;
            bool v = false;
            if (l < L_SEQ) {
                int off = mbase + l;
                if (esz == 1)      v = ((const u8*)xmask)[off] != 0;
                else if (esz == 2) v = ((const u16*)xmask)[off] != 0;
                else               v = ((const u32*)xmask)[off] != 0;
            }
            len += (int)__popcll(__ballot(v));
        }
        if (lane == 0) ((int*)((char*)ws + 24576))[s] = len;
    }
}

// ---- phase A: one wave per (sample, attr); no barriers ----------------------
__global__ __launch_bounds__(64) void etna_attn(
    const int* __restrict__ x, const float* __restrict__ tranb,
    const float* __restrict__ attW, const float* __restrict__ attb,
    void* __restrict__ ws, int Vn) {
    const int bid = blockIdx.x;
    const int s = bid / 3;      // sample (adjacent blocks share s -> L2 reuse)
    const int a = bid - s * 3;  // attribute
    const int lane = threadIdx.x;
    const int col = lane & 15;  // A row m / B+D col n
    const int g = lane >> 4;    // k-chunk / D row group

    // this attr's B-frags: 8 coalesced dwordx4 loads (L2-hot image) -> 32 VGPRs
    const u16* wsBf = (const u16*)ws;
    bf16x8 Bf[4][2];
#pragma unroll
    for (int c = 0; c < 4; ++c)
#pragma unroll
        for (int kh = 0; kh < 2; ++kh)
            Bf[c][kh] = *(const bf16x8*)&wsBf[(((a * 4 + c) * 2 + kh) * 64 + lane) * 8];

    const int len = ((const int*)((const char*)ws + 24576))[s];
    const u16* wsEmb = (const u16*)((const char*)ws + 40960);

    // per-lane constants (C-layout dim = c*16+col); LOG2E folded into AW/AB
    const float LOG2E = 1.44269504088896f;
    float TB[4], AW[4];
#pragma unroll
    for (int c = 0; c < 4; ++c) {
        TB[c] = tranb[a * 64 + c * 16 + col];
        AW[c] = attW[a * 64 + c * 16 + col] * LOG2E;
    }
    const float AB = attb[a] * LOG2E;

    // preload sequence indices (kills idx->gather chain)
    const int* xrow = x + s * L_SEQ;
    int iv[4];
#pragma unroll
    for (int c4 = 0; c4 < 4; ++c4) {
        int l = c4 * 64 + lane;
        int id = (l < L_SEQ) ? xrow[l] : 0;
        iv[c4] = max(0, min(id, Vn - 1));
    }

    float NUM[4] = {0.f, 0.f, 0.f, 0.f};
    float DEN = 0.f;
    const int ntiles = (len + 15) >> 4;

    bf16x8 a0, a1, n0, n1;
    {
        int p = col;
        int id = __shfl(iv[0], p, 64);
        id = (p < len) ? id : 0;  // emb row 0 is all zeros
        const bf16x8* rp = (const bf16x8*)(wsEmb + (size_t)id * 64);
        a0 = rp[g];       // A[m=col][k=g*8+i]
        a1 = rp[4 + g];   // A[m=col][k=32+g*8+i]
    }

    for (int t = 0; t < ntiles; ++t) {
        // 1-deep prefetch of the next tile's rows
        n0 = a0; n1 = a1;
        if (t + 1 < ntiles) {
            int p = (t + 1) * 16 + col;
            int id = __shfl(iv[p >> 6], p & 63, 64);
            id = (p < len) ? id : 0;
            const bf16x8* rn = (const bf16x8*)(wsEmb + (size_t)id * 64);
            n0 = rn[g];
            n1 = rn[4 + g];
        }
        const int l0 = t << 4;

        f32x4 E[4];
#pragma unroll
        for (int c = 0; c < 4; ++c) {
            f32x4 cc = {TB[c], TB[c], TB[c], TB[c]};
            cc = __builtin_amdgcn_mfma_f32_16x16x32_bf16(a0, Bf[c][0], cc, 0, 0, 0);
            cc = __builtin_amdgcn_mfma_f32_16x16x32_bf16(a1, Bf[c][1], cc, 0, 0, 0);
            E[c].x = fmaxf(cc.x, 0.f);
            E[c].y = fmaxf(cc.y, 0.f);
            E[c].z = fmaxf(cc.z, 0.f);
            E[c].w = fmaxf(cc.w, 0.f);
        }
        float p0 = E[0].x * AW[0] + E[1].x * AW[1] + E[2].x * AW[2] + E[3].x * AW[3];
        float p1 = E[0].y * AW[0] + E[1].y * AW[1] + E[2].y * AW[2] + E[3].y * AW[3];
        float p2 = E[0].z * AW[0] + E[1].z * AW[1] + E[2].z * AW[2] + E[3].z * AW[3];
        float p3 = E[0].w * AW[0] + E[1].w * AW[1] + E[2].w * AW[2] + E[3].w * AW[3];
#pragma unroll
        for (int off = 1; off <= 8; off <<= 1) {  // sum 16 cols within group
            p0 += __shfl_xor(p0, off, 64);
            p1 += __shfl_xor(p1, off, 64);
            p2 += __shfl_xor(p2, off, 64);
            p3 += __shfl_xor(p3, off, 64);
        }
        int lrow = l0 + 4 * g;
        float u0 = fmaxf(p0 + AB, 0.f);
        float u1 = fmaxf(p1 + AB, 0.f);
        float u2 = fmaxf(p2 + AB, 0.f);
        float u3 = fmaxf(p3 + AB, 0.f);
        float s0 = (lrow + 0 < len) ? exp2f(u0) : 0.f;
        float s1 = (lrow + 1 < len) ? exp2f(u1) : 0.f;
        float s2 = (lrow + 2 < len) ? exp2f(u2) : 0.f;
        float s3 = (lrow + 3 < len) ? exp2f(u3) : 0.f;
        DEN += s0 + s1 + s2 + s3;
#pragma unroll
        for (int c = 0; c < 4; ++c)
            NUM[c] += s0 * E[c].x + s1 * E[c].y + s2 * E[c].z + s3 * E[c].w;

        a0 = n0;
        a1 = n1;
    }

    // fold the 4 row-groups and store rep[s][a][dim] (f32) to ws
    float* wsRep = (float*)((char*)ws + 40960 + (size_t)Vn * 128);
    {
        float d = DEN;
        d += __shfl_xor(d, 16, 64);
        d += __shfl_xor(d, 32, 64);
        float rden = 1.0f / fmaxf(d, 1e-20f);  // den >= 1 when len >= 1
#pragma unroll
        for (int c = 0; c < 4; ++c) {
            float v = NUM[c];
            v += __shfl_xor(v, 16, 64);
            v += __shfl_xor(v, 32, 64);
            if (g == 0) wsRep[(size_t)s * 192 + a * 64 + c * 16 + col] = tanhf(v * rden);
        }
    }
}

// ---- phase B: wave per sample; proven same-wave LDS epilogue ----------------
__global__ __launch_bounds__(256) void etna_epi(
    const float* __restrict__ ob, const float* __restrict__ W0,
    const float* __restrict__ W1, const float* __restrict__ W2,
    float* __restrict__ out, const void* __restrict__ ws, int Vn) {
    __shared__ float repl[4][3][64];
    const int tid = threadIdx.x;
    const int wv = tid >> 6;
    const int lane = tid & 63;
    const int s = blockIdx.x * 4 + wv;

    const float* wsRep = (const float*)((const char*)ws + 40960 + (size_t)Vn * 128);
#pragma unroll
    for (int a = 0; a < 3; ++a)
        repl[wv][a][lane] = wsRep[(size_t)s * 192 + a * 64 + lane];
    // same-wave LDS write->read (proven R2/R6/R8 float/float pattern)

    float outv = 0.f;
    {
        int gg = lane; float v = repl[wv][gg % 3][gg / 3];
#pragma unroll
        for (int k = 0; k < 2; ++k) {
            float p = wave_sumf(v * W0[lane * 2 + k]);
            if (lane == k) outv = p;
        }
    }
    {
        int gg = 64 + lane; float v = repl[wv][gg % 3][gg / 3];
#pragma unroll
        for (int k = 0; k < 6; ++k) {
            float p = wave_sumf(v * W1[lane * 6 + k]);
            if (lane == 2 + k) outv = p;
        }
    }
    {
        int gg = 128 + lane; float v = repl[wv][gg % 3][gg / 3];
#pragma unroll
        for (int k = 0; k < 10; ++k) {
            float p = wave_sumf(v * W2[lane * 10 + k]);
            if (lane == 8 + k) outv = p;
        }
    }
    if (lane < 18) out[s * 18 + lane] = outv * ob[s * 18 + lane];
}

extern "C" void kernel_launch(void* const* d_in, const int* in_sizes, int n_in,
                              void* d_out, int out_size, void* d_ws, size_t ws_size,
                              hipStream_t stream) {
    const int* x = (const int*)d_in[0];
    const void* xmask = d_in[1];
    // d_in[2] = y : unused
    const float* ob = (const float*)d_in[3];
    const float* emb = (const float*)d_in[4];
    const float* tranW = (const float*)d_in[5];
    const float* tranb = (const float*)d_in[6];
    const float* attW = (const float*)d_in[7];
    const float* attb = (const float*)d_in[8];
    const float* W0 = (const float*)d_in[9];
    const float* W1 = (const float*)d_in[10];
    const float* W2 = (const float*)d_in[11];

    const int Bn = in_sizes[0] / L_SEQ;  // 4096
    const int Vn = in_sizes[4] / 64;     // vocab rows

    etna_prep<<<48 + (Bn + 3) / 4, 256, 0, stream>>>(xmask, tranW, emb, d_ws, Bn, Vn);
    etna_attn<<<Bn * 3, 64, 0, stream>>>(x, tranb, attW, attb, d_ws, Vn);
    etna_epi<<<(Bn + 3) / 4, 256, 0, stream>>>(ob, W0, W1, W2, (float*)d_out, d_ws, Vn);
}

// Round 15
// 136.766 us; speedup vs baseline: 1.0283x; 1.0283x over previous
//
#include <hip/hip_runtime.h>

typedef unsigned int u32;
typedef unsigned short u16;
typedef unsigned char u8;
typedef unsigned long long u64;

typedef __attribute__((ext_vector_type(8))) short bf16x8;
typedef __attribute__((ext_vector_type(4))) float f32x4;
typedef __attribute__((ext_vector_type(4))) u32 u32x4;

#define L_SEQ 200

// Measured: f32 inputs (R6); MFMA 16x16x32_bf16 layouts verified (R6..R14,
// absmax 3.05e-5); low VGPR caps spill (R7); bf16-emb ws table -14us (R11);
// wave=attr -35us (R12). R13/R14 grew ws to ~16MB and R14 failed POST-TIMING
// (corruption signature) -> R15: revert to R12 structure (12.84MB proven
// footprint) and gate all large ws use on measured ws_size.
__device__ __forceinline__ u16 f2bf(float f) {
    u32 u = __float_as_uint(f);
    return (u16)((u + 0x7FFFu + ((u >> 16) & 1u)) >> 16);  // RNE
}
__device__ __forceinline__ u32 pk2bf(float fx, float fy) {  // round-half-up pair pack
    u32 xb = __float_as_uint(fx) + 0x8000u;
    u32 yb = __float_as_uint(fy) + 0x8000u;
    return __byte_perm(xb, yb, 0x7632);
}
__device__ __forceinline__ float wave_sumf(float v) {
#pragma unroll
    for (int off = 32; off; off >>= 1) v += __shfl_xor(v, off, 64);
    return v;
}

// ws layout (bytes): [0,24576) bf16 B-frag image; [24576,40960) len[Bn];
// [40960, 40960+Vn*128) bf16 emb table -- ONLY if ws_size permits (doConv).
__global__ __launch_bounds__(256) void etna_prep(const void* __restrict__ xmask,
                                                 const float* __restrict__ tranW,
                                                 const float* __restrict__ emb,
                                                 void* __restrict__ ws, int Bn, int Vn,
                                                 int doConv) {
    const int tid = threadIdx.x;
    const int bid = blockIdx.x;

    // emb f32 -> bf16 (grid-stride, coalesced u64 stores), gated on ws_size
    if (doConv) {
        u64* dst = (u64*)((char*)ws + 40960);
        const float4* src = (const float4*)emb;
        int ng = Vn * 16;
        for (int i = bid * 256 + tid; i < ng; i += gridDim.x * 256) {
            float4 v = src[i];
            u64 lo = pk2bf(v.x, v.y);
            u64 hi = pk2bf(v.z, v.w);
            dst[i] = lo | (hi << 32);
        }
    }

    if (bid < 48) {
        // B-frag image: element j of frag (a,c,kh,lane) =
        // tranW[a][kh*32+(lane>>4)*8+j][c*16+(lane&15)]  (contiguous writes)
        int it = bid * 256 + tid;
        int jj = it & 7;
        int ln = (it >> 3) & 63;
        int kh = (it >> 9) & 1;
        int c = (it >> 10) & 3;
        int a = it >> 12;
        int k = kh * 32 + (ln >> 4) * 8 + jj;
        int n = c * 16 + (ln & 15);
        ((u16*)ws)[it] = f2bf(tranW[a * 4096 + k * 64 + n]);
        return;
    }

    // x_mask encoding detection (first 800 bytes; safe for u8/bf16/f32/i32)
    const int wv = tid >> 6;
    const int lane = tid & 63;
    int esz;
    {
        u32 accF = 0, acc0 = 0, accO = 0;
#pragma unroll
        for (int k = 0; k < 4; ++k) {
            int i = lane + 64 * k;
            u32 w = (i < 200) ? ((const u32*)xmask)[i] : 0u;
            accF |= (w & 0xFEFEFEFEu);
            acc0 |= (w & 0x000000FFu);
            accO |= (w & 0xFFFFFF00u);
        }
        bool isFloat = __ballot(accF != 0) != 0;
        bool hasB0   = __ballot(acc0 != 0) != 0;
        bool hasOdd  = __ballot(accO != 0) != 0;
        esz = isFloat ? (hasB0 ? 2 : 4) : (hasOdd ? 1 : 4);
    }
    int s = (bid - 48) * 4 + wv;  // one wave per sample
    if (s < Bn) {
        int len = 0;
        int mbase = s * L_SEQ;
#pragma unroll
        for (int c4 = 0; c4 < 4; ++c4) {
            int l = c4 * 64 + lane;
            bool v = false;
            if (l < L_SEQ) {
                int off = mbase + l;
                if (esz == 1)      v = ((const u8*)xmask)[off] != 0;
                else if (esz == 2) v = ((const u16*)xmask)[off] != 0;
                else               v = ((const u32*)xmask)[off] != 0;
            }
            len += (int)__popcll(__ballot(v));
        }
        if (lane == 0) ((int*)((char*)ws + 24576))[s] = len;
    }
}

// ---- main: block = 1 sample = 3 waves; wave wv owns attribute a = wv --------
// TAB=true: gather bf16 rows from ws table (R12-proven). TAB=false: gather f32
// rows from emb and pack (R8-proven) -- used when ws_size is too small.
template <bool TAB>
__global__ __launch_bounds__(192, 4) void etna_mfma(
    const int* __restrict__ x, const float* __restrict__ ob,
    const float* __restrict__ emb, const float* __restrict__ tranb,
    const float* __restrict__ attW, const float* __restrict__ attb,
    const float* __restrict__ W0, const float* __restrict__ W1,
    const float* __restrict__ W2, float* __restrict__ out,
    const void* __restrict__ ws, int Vn) {
    __shared__ float repl[3][64];

    const int tid = threadIdx.x;
    const int a = tid >> 6;     // wave = attribute
    const int lane = tid & 63;
    const int col = lane & 15;  // A row m / B+D col n
    const int g = lane >> 4;    // k-chunk / D row group
    const int b = blockIdx.x;

    // this attr's B-frags: 8 coalesced dwordx4 loads (L2-hot image) -> 32 VGPRs
    const u16* wsBf = (const u16*)ws;
    bf16x8 Bf[4][2];
#pragma unroll
    for (int c = 0; c < 4; ++c)
#pragma unroll
        for (int kh = 0; kh < 2; ++kh)
            Bf[c][kh] = *(const bf16x8*)&wsBf[(((a * 4 + c) * 2 + kh) * 64 + lane) * 8];

    const int len = ((const int*)((const char*)ws + 24576))[b];
    const u16* wsEmb = (const u16*)((const char*)ws + 40960);

    // per-lane constants (C-layout dim = c*16+col); LOG2E folded into AW/AB
    const float LOG2E = 1.44269504088896f;
    float TB[4], AW[4];
#pragma unroll
    for (int c = 0; c < 4; ++c) {
        TB[c] = tranb[a * 64 + c * 16 + col];
        AW[c] = attW[a * 64 + c * 16 + col] * LOG2E;
    }
    const float AB = attb[a] * LOG2E;

    // preload sequence indices (kills idx->gather chain); mask at use time
    const int* xrow = x + b * L_SEQ;
    int iv[4];
#pragma unroll
    for (int c4 = 0; c4 < 4; ++c4) {
        int l = c4 * 64 + lane;
        int id = (l < L_SEQ) ? xrow[l] : 0;
        iv[c4] = max(0, min(id, Vn - 1));
    }

    float NUM[4] = {0.f, 0.f, 0.f, 0.f};
    float DEN = 0.f;
    const int ntiles = (len + 15) >> 4;

    // row loader: A[m=col][k=g*8+i] (a0), A[m=col][k=32+g*8+i] (a1)
    auto loadRow = [&](int id, bf16x8& r0, bf16x8& r1) {
        if (TAB) {
            const bf16x8* rp = (const bf16x8*)(wsEmb + (size_t)id * 64);
            r0 = rp[g];
            r1 = rp[4 + g];
        } else {
            const float4* ep4 = (const float4*)(emb + (size_t)id * 64);
            float4 q0 = ep4[2 * g], q1 = ep4[2 * g + 1];
            float4 q2 = ep4[8 + 2 * g], q3 = ep4[9 + 2 * g];
            u32x4 w0, w1;
            w0.x = pk2bf(q0.x, q0.y); w0.y = pk2bf(q0.z, q0.w);
            w0.z = pk2bf(q1.x, q1.y); w0.w = pk2bf(q1.z, q1.w);
            w1.x = pk2bf(q2.x, q2.y); w1.y = pk2bf(q2.z, q2.w);
            w1.z = pk2bf(q3.x, q3.y); w1.w = pk2bf(q3.z, q3.w);
            r0 = __builtin_bit_cast(bf16x8, w0);
            r1 = __builtin_bit_cast(bf16x8, w1);
        }
    };

    bf16x8 a0, a1, n0, n1;
    {
        int p = col;
        int id = __shfl(iv[0], p, 64);
        id = (p < len) ? id : 0;  // emb row 0 is all zeros
        loadRow(id, a0, a1);
    }

    for (int t = 0; t < ntiles; ++t) {
        // 1-deep prefetch of the next tile's rows
        n0 = a0; n1 = a1;
        if (t + 1 < ntiles) {
            int p = (t + 1) * 16 + col;
            int id = __shfl(iv[p >> 6], p & 63, 64);
            id = (p < len) ? id : 0;
            loadRow(id, n0, n1);
        }
        const int l0 = t << 4;

        f32x4 E[4];
#pragma unroll
        for (int c = 0; c < 4; ++c) {
            f32x4 cc = {TB[c], TB[c], TB[c], TB[c]};
            cc = __builtin_amdgcn_mfma_f32_16x16x32_bf16(a0, Bf[c][0], cc, 0, 0, 0);
            cc = __builtin_amdgcn_mfma_f32_16x16x32_bf16(a1, Bf[c][1], cc, 0, 0, 0);
            E[c].x = fmaxf(cc.x, 0.f);
            E[c].y = fmaxf(cc.y, 0.f);
            E[c].z = fmaxf(cc.z, 0.f);
            E[c].w = fmaxf(cc.w, 0.f);
        }
        float p0 = E[0].x * AW[0] + E[1].x * AW[1] + E[2].x * AW[2] + E[3].x * AW[3];
        float p1 = E[0].y * AW[0] + E[1].y * AW[1] + E[2].y * AW[2] + E[3].y * AW[3];
        float p2 = E[0].z * AW[0] + E[1].z * AW[1] + E[2].z * AW[2] + E[3].z * AW[3];
        float p3 = E[0].w * AW[0] + E[1].w * AW[1] + E[2].w * AW[2] + E[3].w * AW[3];
#pragma unroll
        for (int off = 1; off <= 8; off <<= 1) {  // sum 16 cols within group
            p0 += __shfl_xor(p0, off, 64);
            p1 += __shfl_xor(p1, off, 64);
            p2 += __shfl_xor(p2, off, 64);
            p3 += __shfl_xor(p3, off, 64);
        }
        int lrow = l0 + 4 * g;
        float u0 = fmaxf(p0 + AB, 0.f);
        float u1 = fmaxf(p1 + AB, 0.f);
        float u2 = fmaxf(p2 + AB, 0.f);
        float u3 = fmaxf(p3 + AB, 0.f);
        float s0 = (lrow + 0 < len) ? exp2f(u0) : 0.f;
        float s1 = (lrow + 1 < len) ? exp2f(u1) : 0.f;
        float s2 = (lrow + 2 < len) ? exp2f(u2) : 0.f;
        float s3 = (lrow + 3 < len) ? exp2f(u3) : 0.f;
        DEN += s0 + s1 + s2 + s3;
#pragma unroll
        for (int c = 0; c < 4; ++c)
            NUM[c] += s0 * E[c].x + s1 * E[c].y + s2 * E[c].z + s3 * E[c].w;

        a0 = n0;
        a1 = n1;
    }

    // fold the 4 row-groups -> wave-total; this wave owns its attr completely
    {
        float d = DEN;
        d += __shfl_xor(d, 16, 64);
        d += __shfl_xor(d, 32, 64);
        float rden = 1.0f / fmaxf(d, 1e-20f);  // den >= 1 when len >= 1
#pragma unroll
        for (int c = 0; c < 4; ++c) {
            float v = NUM[c];
            v += __shfl_xor(v, 16, 64);
            v += __shfl_xor(v, 32, 64);
            if (g == 0) repl[a][c * 16 + col] = tanhf(v * rden);
        }
    }
    __syncthreads();

    if (a == 0) {
        // epilogue: torch interleave u[3d+aa]=rep[aa][d]; segment s -> u[64s:64s+64]@Ws
        float outv = 0.f;
        {
            int gg = lane; float v = repl[gg % 3][gg / 3];
#pragma unroll
            for (int k = 0; k < 2; ++k) {
                float p = wave_sumf(v * W0[lane * 2 + k]);
                if (lane == k) outv = p;
            }
        }
        {
            int gg = 64 + lane; float v = repl[gg % 3][gg / 3];
#pragma unroll
            for (int k = 0; k < 6; ++k) {
                float p = wave_sumf(v * W1[lane * 6 + k]);
                if (lane == 2 + k) outv = p;
            }
        }
        {
            int gg = 128 + lane; float v = repl[gg % 3][gg / 3];
#pragma unroll
            for (int k = 0; k < 10; ++k) {
                float p = wave_sumf(v * W2[lane * 10 + k]);
                if (lane == 8 + k) outv = p;
            }
        }
        if (lane < 18) out[b * 18 + lane] = outv * ob[b * 18 + lane];
    }
}

extern "C" void kernel_launch(void* const* d_in, const int* in_sizes, int n_in,
                              void* d_out, int out_size, void* d_ws, size_t ws_size,
                              hipStream_t stream) {
    const int* x = (const int*)d_in[0];
    const void* xmask = d_in[1];
    // d_in[2] = y : unused
    const float* ob = (const float*)d_in[3];
    const float* emb = (const float*)d_in[4];
    const float* tranW = (const float*)d_in[5];
    const float* tranb = (const float*)d_in[6];
    const float* attW = (const float*)d_in[7];
    const float* attb = (const float*)d_in[8];
    const float* W0 = (const float*)d_in[9];
    const float* W1 = (const float*)d_in[10];
    const float* W2 = (const float*)d_in[11];

    const int Bn = in_sizes[0] / L_SEQ;  // 4096
    const int Vn = in_sizes[4] / 64;     // vocab rows

    // gate the 12.8MB emb bf16 table on the ACTUAL workspace size (constant
    // across calls -> same work every launch, graph-capture safe)
    const size_t need = 40960 + (size_t)Vn * 128;
    const int useTab = (ws_size >= need) ? 1 : 0;

    etna_prep<<<48 + (Bn + 3) / 4, 256, 0, stream>>>(xmask, tranW, emb, d_ws, Bn, Vn, useTab);
    if (useTab)
        etna_mfma<true><<<Bn, 192, 0, stream>>>(x, ob, emb, tranb, attW, attb,
                                                W0, W1, W2, (float*)d_out, d_ws, Vn);
    else
        etna_mfma<false><<<Bn, 192, 0, stream>>>(x, ob, emb, tranb, attW, attb,
                                                 W0, W1, W2, (float*)d_out, d_ws, Vn);
}